// Round 1
// 362.896 us; speedup vs baseline: 1.0400x; 1.0400x over previous
//
#include <hip/hip_runtime.h>
#include <hip/hip_bf16.h>
#include <cstdint>

// Problem dims (fixed by reference setup_inputs)
constexpr int Bc  = 2;
constexpr int Lc  = 4096;
constexpr int Hc  = 2048;
constexpr int LKc = 128;
constexpr float LAMc = 0.003f;

typedef __attribute__((ext_vector_type(8))) __bf16 bf16x8;
typedef __attribute__((ext_vector_type(4))) float  f32x4;
typedef __attribute__((ext_vector_type(8))) unsigned short ushort8;

__device__ __forceinline__ unsigned short f2bf_bits(float v) {
  union { __hip_bfloat16 b; unsigned short u; } cv;
  cv.b = __float2bfloat16(v);
  return cv.u;
}
__device__ __forceinline__ float bf_bits2f(unsigned short u) {
  union { unsigned int i; float f; } cv;
  cv.i = ((unsigned int)u) << 16;
  return cv.f;
}

// ---------------------------------------------------------------------------
// async global->LDS, 16B per lane. LDS dest is the WAVE-UNIFORM base; HW adds
// lane*16. Global src is per-lane (pre-gathered fragment order).
// ---------------------------------------------------------------------------
__device__ __forceinline__ void gl_lds16(const void* g, void* lds) {
  __builtin_amdgcn_global_load_lds(
      (const __attribute__((address_space(1))) uint32_t*)(uintptr_t)g,
      (__attribute__((address_space(3))) uint32_t*)(uint32_t)(uintptr_t)lds,
      16, 0, 0);
}

// ---------------------------------------------------------------------------
// Kernel 1: tap squash + Hankel MFMA A-fragment precompute (unchanged).
// ---------------------------------------------------------------------------
__global__ __launch_bounds__(256) void tapfrag_kernel(
    const float* __restrict__ kin, unsigned short* __restrict__ Afr) {
  const int idx  = blockIdx.x * 256 + threadIdx.x;  // [0, 2048*5*64)
  const int lane = idx & 63;
  const int idx2 = idx >> 6;          // h*5 + cc
  const int h  = idx2 / 5;
  const int cc = idx2 - h * 5;
  const int m = lane & 15, quad = lane >> 4;
  const int jb = m + 32 * cc - 32 + 8 * quad;
  ushort8 o;
#pragma unroll
  for (int jj = 0; jj < 8; ++jj) {
    const int j = jb + jj;
    float v = 0.f;
    if (j >= 0 && j < LKc) {
      const float x = kin[h * LKc + j];
      const float a = fabsf(x) - LAMc;
      v = (a > 0.f) ? copysignf(a, x) : 0.f;
    }
    o[jj] = f2bf_bits(v);
  }
  ((ushort8*)Afr)[idx] = o;
}

// ---------------------------------------------------------------------------
// Kernel 2: W fp32 [2H, H] -> bf16 same layout (unchanged).
// ---------------------------------------------------------------------------
__global__ __launch_bounds__(256) void wcast_kernel(
    const float* __restrict__ W, __hip_bfloat16* __restrict__ Wb) {
  const int idx = (blockIdx.x * 256 + threadIdx.x) * 4;
  const float4 v = *(const float4*)(W + idx);
  Wb[idx + 0] = __float2bfloat16(v.x);
  Wb[idx + 1] = __float2bfloat16(v.y);
  Wb[idx + 2] = __float2bfloat16(v.z);
  Wb[idx + 3] = __float2bfloat16(v.w);
}

// ---------------------------------------------------------------------------
// Kernel 3: MFMA FIR conv (unchanged this round).
// ---------------------------------------------------------------------------
__global__ __launch_bounds__(256) void conv_mfma_kernel(
    const float* __restrict__ u, const unsigned short* __restrict__ Afr,
    const float* __restrict__ Dp, unsigned short* __restrict__ Am) {
  __shared__ __align__(16) unsigned short ur[16 * 664];  // 21248 B
  __shared__ __align__(16) unsigned short ot[512 * 17];  // 17408 B

  const int t    = threadIdx.x;
  const int lane = t & 63;
  const int wv   = t >> 6;
  const int l16  = lane & 15;
  const int quad = lane >> 4;
  const int l0 = blockIdx.x * 512;
  const int h0 = blockIdx.y * 16;
  const int b  = blockIdx.z;

  const size_t ubase = (size_t)b * Lc * Hc + h0;

#pragma unroll 4
  for (int i = 0; i < 41; ++i) {
    const int e  = (i << 8) + t;
    const int hl = e & 15;
    const int x  = e >> 4;
    const int l  = l0 + 528 - x;
    float v = 0.f;
    if (l >= 0) v = u[ubase + (size_t)min(l, Lc - 1) * Hc + hl];
    ur[hl * 664 + x] = f2bf_bits(v);
  }
  __syncthreads();

#pragma unroll 1
  for (int hi = 0; hi < 4; ++hi) {
    const int hl = (wv << 2) | hi;
    const int h  = h0 + hl;
    bf16x8 af[5];
    const unsigned short* afp = Afr + ((size_t)(h * 5) * 64 + lane) * 8;
#pragma unroll
    for (int cc = 0; cc < 5; ++cc) af[cc] = *(const bf16x8*)(afp + cc * 512);
    const float dv = 2.f * Dp[h];
    const unsigned short* urh = &ur[hl * 664];
#pragma unroll
    for (int nt = 0; nt < 2; ++nt) {
      f32x4 acc = f32x4{0.f, 0.f, 0.f, 0.f};
      const int bbase = 496 - 256 * nt - 16 * l16 + 8 * quad;
#pragma unroll
      for (int cc = 0; cc < 5; ++cc) {
        const bf16x8 bf = *(const bf16x8*)(urh + bbase + 32 * cc);
        acc = __builtin_amdgcn_mfma_f32_16x16x32_bf16(af[cc], bf, acc, 0, 0, 0);
      }
#pragma unroll
      for (int r = 0; r < 4; ++r) {
        const int lc = quad * 4 + r + 16 * l16;
        const float uu = bf_bits2f(urh[528 - 256 * nt - lc]);
        const float y = fmaf(dv, uu, acc[r]);
        const float g = 0.5f * y * (1.f + erff(y * 0.70710678118654752f));
        ot[(nt * 256 + lc) * 17 + hl] = f2bf_bits(g);
      }
    }
  }
  __syncthreads();

#pragma unroll
  for (int rr = 0; rr < 2; ++rr) {
    const int lc = (rr << 8) + t;
    const unsigned short* row = &ot[lc * 17];
    unsigned int w[8];
#pragma unroll
    for (int p = 0; p < 8; ++p)
      w[p] = (unsigned int)row[2 * p] | ((unsigned int)row[2 * p + 1] << 16);
    unsigned short* dst = Am + ((size_t)(b * Lc + l0 + lc)) * Hc + h0;
    *(uint4*)(dst)     = make_uint4(w[0], w[1], w[2], w[3]);
    *(uint4*)(dst + 8) = make_uint4(w[4], w[5], w[6], w[7]);
  }
}

// ---------------------------------------------------------------------------
// Kernel 4 (v2): 8-phase-style GEMM + bias + GLU.
//  - tile 256M x 128N-out (a+g interleaved -> effective 256x256), 8 waves
//  - BK=32, 4-slot LDS ring (128 KiB), staged 2 K-tiles ahead
//  - counted s_waitcnt vmcnt(4) at K-tile boundary (never 0 in steady state)
//  - fragment-packed LDS via per-lane pre-gathered global_load_lds sources:
//    frag f lives at a contiguous 1KB run -> conflict-free ds_read_b128
//  - raw s_barrier + lgkmcnt(0) + s_setprio(1) around each 16-MFMA cluster
//  - XCD-aware blockIdx swizzle (512 % 8 == 0 -> simple form valid)
//
// B-tile column order: tile col c in [0,256): wc=c>>6 half=(c>>5)&1 c32=c&31
//   -> W row = half*Hc + n0 + wc*32 + c32.  Wave wc thus owns matching a/g
//   columns (nf 0,1 = a; nf 2,3 = g) so the GLU epilogue is lane-local.
// ---------------------------------------------------------------------------
constexpr int KTILES = Hc / 32;  // 64

__global__ __launch_bounds__(512, 2) void gemm_glu_kernel(
    const __hip_bfloat16* __restrict__ A, const __hip_bfloat16* __restrict__ Wb,
    const float* __restrict__ bias, float* __restrict__ out) {
  __shared__ __align__(16) char lds[131072];  // 4 slots x (A 16KB + B 16KB)

  const int t    = threadIdx.x;
  const int lane = t & 63;
  const int w    = t >> 6;        // wave 0..7
  const int l16  = lane & 15;
  const int quad = lane >> 4;
  const int wr   = w >> 2;        // 0..1 : M band
  const int wc   = w & 3;         // 0..3 : N band

  const int bid = blockIdx.x;                 // 0..511
  const int wg  = (bid & 7) * 64 + (bid >> 3);  // XCD swizzle
  const int m0g = (wg & 31) * 256;
  const int n0  = (wg >> 5) * 128;

  // per-thread pre-gathered staging sources: idx 0,1 = A units, 2,3 = B units
  const __hip_bfloat16* gsrc[4];
#pragma unroll
  for (int u = 0; u < 2; ++u) {
    const int f = u * 8 + w;  // fragment index 0..15 staged by this wave
    gsrc[u] = A + (size_t)(m0g + f * 16 + l16) * Hc + quad * 8;
    const int wrow = ((f >> 1) & 1) * Hc + n0 + (f >> 2) * 32 + (f & 1) * 16 + l16;
    gsrc[2 + u] = Wb + (size_t)wrow * Hc + quad * 8;
  }

  f32x4 acc[8][4];
#pragma unroll
  for (int i = 0; i < 8; ++i)
#pragma unroll
    for (int j = 0; j < 4; ++j) acc[i][j] = f32x4{0.f, 0.f, 0.f, 0.f};

// wave-uniform LDS dest: slot + region + frag run; HW adds lane*16
#define STAGE(tile, idx)                                                      \
  gl_lds16(gsrc[idx] + (size_t)(tile) * 32,                                   \
           lds + ((tile) & 3) * 32768 + (((idx) >> 1) & 1) * 16384 +          \
               (((idx) & 1) * 8 + w) * 1024)

  // prologue: K-tiles 0 and 1 (4 loads/lane each)
#pragma unroll
  for (int i = 0; i < 4; ++i) STAGE(0, i);
#pragma unroll
  for (int i = 0; i < 4; ++i) STAGE(1, i);
  asm volatile("s_waitcnt vmcnt(4)" ::: "memory");  // tile 0 landed
  __builtin_amdgcn_s_barrier();

  const char* sAbase = lds + wr * 8192 + lane * 16;
  const char* sBbase = lds + 16384 + wc * 4096 + lane * 16;

#pragma unroll 2
  for (int kt = 0; kt < KTILES; ++kt) {
    const int slot = (kt & 3) * 32768;
    const char* sA = sAbase + slot;
    const char* sB = sBbase + slot;
    bf16x8 afr[4], bfr[4];

    // ---------- phase 0: A-frags 0..3, all B-frags; stage A units of kt+2
#pragma unroll
    for (int i = 0; i < 4; ++i) afr[i] = *(const bf16x8*)(sA + i * 1024);
#pragma unroll
    for (int i = 0; i < 4; ++i) bfr[i] = *(const bf16x8*)(sB + i * 1024);
    if (kt + 2 < KTILES) { STAGE(kt + 2, 0); STAGE(kt + 2, 1); }
    __builtin_amdgcn_s_barrier();
    asm volatile("s_waitcnt lgkmcnt(0)" ::: "memory");
    __builtin_amdgcn_s_setprio(1);
#pragma unroll
    for (int mf = 0; mf < 4; ++mf)
#pragma unroll
      for (int nf = 0; nf < 4; ++nf)
        acc[mf][nf] = __builtin_amdgcn_mfma_f32_16x16x32_bf16(
            afr[mf], bfr[nf], acc[mf][nf], 0, 0, 0);
    __builtin_amdgcn_s_setprio(0);
    __builtin_amdgcn_s_barrier();

    // ---------- phase 1: A-frags 4..7; stage B units of kt+2
#pragma unroll
    for (int i = 0; i < 4; ++i) afr[i] = *(const bf16x8*)(sA + (4 + i) * 1024);
    if (kt + 2 < KTILES) { STAGE(kt + 2, 2); STAGE(kt + 2, 3); }
    __builtin_amdgcn_s_barrier();
    asm volatile("s_waitcnt lgkmcnt(0)" ::: "memory");
    __builtin_amdgcn_s_setprio(1);
#pragma unroll
    for (int mf = 0; mf < 4; ++mf)
#pragma unroll
      for (int nf = 0; nf < 4; ++nf)
        acc[4 + mf][nf] = __builtin_amdgcn_mfma_f32_16x16x32_bf16(
            afr[mf], bfr[nf], acc[4 + mf][nf], 0, 0, 0);
    __builtin_amdgcn_s_setprio(0);
    // K-tile boundary: ensure kt+1 fully in LDS; kt+2's 4 loads stay in flight
    if (kt < KTILES - 2) asm volatile("s_waitcnt vmcnt(4)" ::: "memory");
    else                 asm volatile("s_waitcnt vmcnt(0)" ::: "memory");
    __builtin_amdgcn_s_barrier();
  }
#undef STAGE

  // ---------- epilogue: lane-local GLU (a at nf, g at nf+2), coalesced rows
  const int mwb = m0g + wr * 128 + quad * 4;
  const int nb  = n0 + wc * 32 + l16;
#pragma unroll
  for (int j = 0; j < 2; ++j) {
    const int n = nb + j * 16;
    const float ba = bias[n];
    const float bg = bias[Hc + n];
#pragma unroll
    for (int mf = 0; mf < 8; ++mf) {
#pragma unroll
      for (int r = 0; r < 4; ++r) {
        const float a = acc[mf][j][r] + ba;
        const float g = acc[mf][j + 2][r] + bg;
        out[(size_t)(mwb + mf * 16 + r) * Hc + n] = a * (1.f / (1.f + expf(-g)));
      }
    }
  }
}

// ---------------------------------------------------------------------------
extern "C" void kernel_launch(void* const* d_in, const int* in_sizes, int n_in,
                              void* d_out, int out_size, void* d_ws, size_t ws_size,
                              hipStream_t stream) {
  const float* u    = (const float*)d_in[0];  // [B, L, H]
  const float* kin  = (const float*)d_in[1];  // [1, H, LK]
  const float* Dp   = (const float*)d_in[2];  // [1, H]
  const float* W    = (const float*)d_in[3];  // [2H, H]
  const float* bias = (const float*)d_in[4];  // [2H]
  float* out = (float*)d_out;                 // [B, L, H]

  // ws layout:
  //   [0, 10.5MB)  Afr  (tap fragments; dead after conv)
  //   [0, 16MB)    Wb   (bf16 W; written AFTER conv reads Afr -- same stream)
  //   [16MB, 48MB) Am   (bf16 activations)
  char* ws = (char*)d_ws;
  unsigned short* Afr = (unsigned short*)ws;
  __hip_bfloat16* Wb  = (__hip_bfloat16*)ws;
  unsigned short* Am  = (unsigned short*)(ws + (16 << 20));

  tapfrag_kernel<<<(Hc * 5 * 64) / 256, 256, 0, stream>>>(kin, Afr);
  conv_mfma_kernel<<<dim3(Lc / 512, Hc / 16, Bc), 256, 0, stream>>>(u, Afr, Dp, Am);
  wcast_kernel<<<(2 * Hc * Hc) / 1024, 256, 0, stream>>>(W, Wb);
  gemm_glu_kernel<<<dim3((Bc * Lc / 256) * (Hc / 128)), 512, 0, stream>>>(
      (const __hip_bfloat16*)Am, Wb, bias, out);
}

// Round 2
// 359.574 us; speedup vs baseline: 1.0496x; 1.0092x over previous
//
#include <hip/hip_runtime.h>
#include <hip/hip_bf16.h>
#include <cstdint>

// Problem dims (fixed by reference setup_inputs)
constexpr int Bc  = 2;
constexpr int Lc  = 4096;
constexpr int Hc  = 2048;
constexpr int LKc = 128;
constexpr float LAMc = 0.003f;

typedef __attribute__((ext_vector_type(8))) __bf16 bf16x8;
typedef __attribute__((ext_vector_type(4))) float  f32x4;
typedef __attribute__((ext_vector_type(8))) unsigned short ushort8;

__device__ __forceinline__ unsigned short f2bf_bits(float v) {
  union { __hip_bfloat16 b; unsigned short u; } cv;
  cv.b = __float2bfloat16(v);
  return cv.u;
}
__device__ __forceinline__ float bf_bits2f(unsigned short u) {
  union { unsigned int i; float f; } cv;
  cv.i = ((unsigned int)u) << 16;
  return cv.f;
}

// ---------------------------------------------------------------------------
// async global->LDS, 16B per lane. LDS dest is the WAVE-UNIFORM base; HW adds
// lane*16. Global src is per-lane (pre-gathered fragment order).
// ---------------------------------------------------------------------------
__device__ __forceinline__ void gl_lds16(const void* g, void* lds) {
  __builtin_amdgcn_global_load_lds(
      (const __attribute__((address_space(1))) uint32_t*)(uintptr_t)g,
      (__attribute__((address_space(3))) uint32_t*)(uint32_t)(uintptr_t)lds,
      16, 0, 0);
}

// ---------------------------------------------------------------------------
// Kernel 1: tap squash + Hankel MFMA A-fragment precompute (unchanged).
// ---------------------------------------------------------------------------
__global__ __launch_bounds__(256) void tapfrag_kernel(
    const float* __restrict__ kin, unsigned short* __restrict__ Afr) {
  const int idx  = blockIdx.x * 256 + threadIdx.x;  // [0, 2048*5*64)
  const int lane = idx & 63;
  const int idx2 = idx >> 6;          // h*5 + cc
  const int h  = idx2 / 5;
  const int cc = idx2 - h * 5;
  const int m = lane & 15, quad = lane >> 4;
  const int jb = m + 32 * cc - 32 + 8 * quad;
  ushort8 o;
#pragma unroll
  for (int jj = 0; jj < 8; ++jj) {
    const int j = jb + jj;
    float v = 0.f;
    if (j >= 0 && j < LKc) {
      const float x = kin[h * LKc + j];
      const float a = fabsf(x) - LAMc;
      v = (a > 0.f) ? copysignf(a, x) : 0.f;
    }
    o[jj] = f2bf_bits(v);
  }
  ((ushort8*)Afr)[idx] = o;
}

// ---------------------------------------------------------------------------
// Kernel 2: W fp32 [2H, H] -> bf16 same layout (unchanged).
// ---------------------------------------------------------------------------
__global__ __launch_bounds__(256) void wcast_kernel(
    const float* __restrict__ W, __hip_bfloat16* __restrict__ Wb) {
  const int idx = (blockIdx.x * 256 + threadIdx.x) * 4;
  const float4 v = *(const float4*)(W + idx);
  Wb[idx + 0] = __float2bfloat16(v.x);
  Wb[idx + 1] = __float2bfloat16(v.y);
  Wb[idx + 2] = __float2bfloat16(v.z);
  Wb[idx + 3] = __float2bfloat16(v.w);
}

// ---------------------------------------------------------------------------
// Kernel 3: MFMA FIR conv (unchanged this round).
// ---------------------------------------------------------------------------
__global__ __launch_bounds__(256) void conv_mfma_kernel(
    const float* __restrict__ u, const unsigned short* __restrict__ Afr,
    const float* __restrict__ Dp, unsigned short* __restrict__ Am) {
  __shared__ __align__(16) unsigned short ur[16 * 664];  // 21248 B
  __shared__ __align__(16) unsigned short ot[512 * 17];  // 17408 B

  const int t    = threadIdx.x;
  const int lane = t & 63;
  const int wv   = t >> 6;
  const int l16  = lane & 15;
  const int quad = lane >> 4;
  const int l0 = blockIdx.x * 512;
  const int h0 = blockIdx.y * 16;
  const int b  = blockIdx.z;

  const size_t ubase = (size_t)b * Lc * Hc + h0;

#pragma unroll 4
  for (int i = 0; i < 41; ++i) {
    const int e  = (i << 8) + t;
    const int hl = e & 15;
    const int x  = e >> 4;
    const int l  = l0 + 528 - x;
    float v = 0.f;
    if (l >= 0) v = u[ubase + (size_t)min(l, Lc - 1) * Hc + hl];
    ur[hl * 664 + x] = f2bf_bits(v);
  }
  __syncthreads();

#pragma unroll 1
  for (int hi = 0; hi < 4; ++hi) {
    const int hl = (wv << 2) | hi;
    const int h  = h0 + hl;
    bf16x8 af[5];
    const unsigned short* afp = Afr + ((size_t)(h * 5) * 64 + lane) * 8;
#pragma unroll
    for (int cc = 0; cc < 5; ++cc) af[cc] = *(const bf16x8*)(afp + cc * 512);
    const float dv = 2.f * Dp[h];
    const unsigned short* urh = &ur[hl * 664];
#pragma unroll
    for (int nt = 0; nt < 2; ++nt) {
      f32x4 acc = f32x4{0.f, 0.f, 0.f, 0.f};
      const int bbase = 496 - 256 * nt - 16 * l16 + 8 * quad;
#pragma unroll
      for (int cc = 0; cc < 5; ++cc) {
        const bf16x8 bf = *(const bf16x8*)(urh + bbase + 32 * cc);
        acc = __builtin_amdgcn_mfma_f32_16x16x32_bf16(af[cc], bf, acc, 0, 0, 0);
      }
#pragma unroll
      for (int r = 0; r < 4; ++r) {
        const int lc = quad * 4 + r + 16 * l16;
        const float uu = bf_bits2f(urh[528 - 256 * nt - lc]);
        const float y = fmaf(dv, uu, acc[r]);
        const float g = 0.5f * y * (1.f + erff(y * 0.70710678118654752f));
        ot[(nt * 256 + lc) * 17 + hl] = f2bf_bits(g);
      }
    }
  }
  __syncthreads();

#pragma unroll
  for (int rr = 0; rr < 2; ++rr) {
    const int lc = (rr << 8) + t;
    const unsigned short* row = &ot[lc * 17];
    unsigned int w[8];
#pragma unroll
    for (int p = 0; p < 8; ++p)
      w[p] = (unsigned int)row[2 * p] | ((unsigned int)row[2 * p + 1] << 16);
    unsigned short* dst = Am + ((size_t)(b * Lc + l0 + lc)) * Hc + h0;
    *(uint4*)(dst)     = make_uint4(w[0], w[1], w[2], w[3]);
    *(uint4*)(dst + 8) = make_uint4(w[4], w[5], w[6], w[7]);
  }
}

// ---------------------------------------------------------------------------
// Kernel 4 (v3): 8-phase GEMM + bias + GLU with sched_barrier(0) phase pins.
//  - tile 256M x 128N-out (a+g interleaved), 8 waves, BK=32
//  - 4-slot LDS ring (128 KiB), staged 2 K-tiles ahead, vmcnt(4) boundary wait
//  - fragment-packed LDS (pre-gathered gl_lds sources) -> 0 bank conflicts (r1)
//  - NEW: sched_barrier(0) pins stop hipcc from sinking ds_reads past barriers
//    / hoisting MFMAs past lgkmcnt(0) (rule #18) -> phases stay interleaved
//  - NEW: branch-free main loop (staging predicate split into 2-tile epilogue)
// ---------------------------------------------------------------------------
constexpr int KTILES = Hc / 32;  // 64

__global__ __launch_bounds__(512, 2) void gemm_glu_kernel(
    const __hip_bfloat16* __restrict__ A, const __hip_bfloat16* __restrict__ Wb,
    const float* __restrict__ bias, float* __restrict__ out) {
  __shared__ __align__(16) char lds[131072];  // 4 slots x (A 16KB + B 16KB)

  const int t    = threadIdx.x;
  const int lane = t & 63;
  const int w    = t >> 6;        // wave 0..7
  const int l16  = lane & 15;
  const int quad = lane >> 4;
  const int wr   = w >> 2;        // 0..1 : M band
  const int wc   = w & 3;         // 0..3 : N band

  const int bid = blockIdx.x;                   // 0..511
  const int wg  = (bid & 7) * 64 + (bid >> 3);  // XCD swizzle (512 % 8 == 0)
  const int m0g = (wg & 31) * 256;
  const int n0  = (wg >> 5) * 128;

  // per-thread pre-gathered staging sources: idx 0,1 = A units, 2,3 = B units
  const __hip_bfloat16* gsrc[4];
#pragma unroll
  for (int u = 0; u < 2; ++u) {
    const int f = u * 8 + w;  // fragment index 0..15 staged by this wave
    gsrc[u] = A + (size_t)(m0g + f * 16 + l16) * Hc + quad * 8;
    const int wrow = ((f >> 1) & 1) * Hc + n0 + (f >> 2) * 32 + (f & 1) * 16 + l16;
    gsrc[2 + u] = Wb + (size_t)wrow * Hc + quad * 8;
  }

  f32x4 acc[8][4];
#pragma unroll
  for (int i = 0; i < 8; ++i)
#pragma unroll
    for (int j = 0; j < 4; ++j) acc[i][j] = f32x4{0.f, 0.f, 0.f, 0.f};

// wave-uniform LDS dest: slot + region + frag run; HW adds lane*16
#define STAGE(tile, idx)                                                      \
  gl_lds16(gsrc[idx] + (size_t)(tile) * 32,                                   \
           lds + ((tile) & 3) * 32768 + (((idx) >> 1) & 1) * 16384 +          \
               (((idx) & 1) * 8 + w) * 1024)

  // prologue: K-tiles 0 and 1 (4 loads/lane each)
#pragma unroll
  for (int i = 0; i < 4; ++i) STAGE(0, i);
#pragma unroll
  for (int i = 0; i < 4; ++i) STAGE(1, i);
  asm volatile("s_waitcnt vmcnt(4)" ::: "memory");  // tile 0 landed
  __builtin_amdgcn_s_barrier();

  const char* sAbase = lds + wr * 8192 + lane * 16;
  const char* sBbase = lds + 16384 + wc * 4096 + lane * 16;

  // One BK=32 K-tile: 2 phases of {ds_read || stage -> barrier -> lgkmcnt(0)
  // -> 16 MFMA -> barrier}, vmcnt(VMN) boundary wait. sched_barrier(0) pins
  // keep the compiler from collapsing the phase structure.
#define KTILE_BODY(KT, DO_STAGE, VMN)                                         \
  {                                                                           \
    const char* sA = sAbase + ((KT) & 3) * 32768;                             \
    const char* sB = sBbase + ((KT) & 3) * 32768;                             \
    bf16x8 afr[4], bfr[4];                                                    \
    _Pragma("unroll") for (int i = 0; i < 4; ++i)                             \
        afr[i] = *(const bf16x8*)(sA + i * 1024);                             \
    _Pragma("unroll") for (int i = 0; i < 4; ++i)                             \
        bfr[i] = *(const bf16x8*)(sB + i * 1024);                             \
    if (DO_STAGE) { STAGE((KT) + 2, 0); STAGE((KT) + 2, 1); }                 \
    __builtin_amdgcn_sched_barrier(0);                                        \
    __builtin_amdgcn_s_barrier();                                             \
    asm volatile("s_waitcnt lgkmcnt(0)" ::: "memory");                        \
    __builtin_amdgcn_sched_barrier(0);                                        \
    __builtin_amdgcn_s_setprio(1);                                            \
    _Pragma("unroll") for (int mf = 0; mf < 4; ++mf)                          \
        _Pragma("unroll") for (int nf = 0; nf < 4; ++nf)                      \
            acc[mf][nf] = __builtin_amdgcn_mfma_f32_16x16x32_bf16(            \
                afr[mf], bfr[nf], acc[mf][nf], 0, 0, 0);                      \
    __builtin_amdgcn_s_setprio(0);                                            \
    __builtin_amdgcn_sched_barrier(0);                                        \
    __builtin_amdgcn_s_barrier();                                             \
    _Pragma("unroll") for (int i = 0; i < 4; ++i)                             \
        afr[i] = *(const bf16x8*)(sA + (4 + i) * 1024);                       \
    if (DO_STAGE) { STAGE((KT) + 2, 2); STAGE((KT) + 2, 3); }                 \
    __builtin_amdgcn_sched_barrier(0);                                        \
    __builtin_amdgcn_s_barrier();                                             \
    asm volatile("s_waitcnt lgkmcnt(0)" ::: "memory");                        \
    __builtin_amdgcn_sched_barrier(0);                                        \
    __builtin_amdgcn_s_setprio(1);                                            \
    _Pragma("unroll") for (int mf = 0; mf < 4; ++mf)                          \
        _Pragma("unroll") for (int nf = 0; nf < 4; ++nf)                      \
            acc[4 + mf][nf] = __builtin_amdgcn_mfma_f32_16x16x32_bf16(        \
                afr[mf], bfr[nf], acc[4 + mf][nf], 0, 0, 0);                  \
    __builtin_amdgcn_s_setprio(0);                                            \
    asm volatile("s_waitcnt vmcnt(" #VMN ")" ::: "memory");                   \
    __builtin_amdgcn_sched_barrier(0);                                        \
    __builtin_amdgcn_s_barrier();                                             \
  }

#pragma unroll 1
  for (int kt = 0; kt < KTILES - 2; ++kt) KTILE_BODY(kt, true, 4)
  // epilogue: last 2 tiles, no staging; drain remaining loads at first boundary
  KTILE_BODY(KTILES - 2, false, 0)
  KTILE_BODY(KTILES - 1, false, 0)
#undef KTILE_BODY
#undef STAGE

  // ---------- epilogue: lane-local GLU (a at nf, g at nf+2), coalesced rows
  const int mwb = m0g + wr * 128 + quad * 4;
  const int nb  = n0 + wc * 32 + l16;
#pragma unroll
  for (int j = 0; j < 2; ++j) {
    const int n = nb + j * 16;
    const float ba = bias[n];
    const float bg = bias[Hc + n];
#pragma unroll
    for (int mf = 0; mf < 8; ++mf) {
#pragma unroll
      for (int r = 0; r < 4; ++r) {
        const float a = acc[mf][j][r] + ba;
        const float g = acc[mf][j + 2][r] + bg;
        out[(size_t)(mwb + mf * 16 + r) * Hc + n] = a * (1.f / (1.f + expf(-g)));
      }
    }
  }
}

// ---------------------------------------------------------------------------
extern "C" void kernel_launch(void* const* d_in, const int* in_sizes, int n_in,
                              void* d_out, int out_size, void* d_ws, size_t ws_size,
                              hipStream_t stream) {
  const float* u    = (const float*)d_in[0];  // [B, L, H]
  const float* kin  = (const float*)d_in[1];  // [1, H, LK]
  const float* Dp   = (const float*)d_in[2];  // [1, H]
  const float* W    = (const float*)d_in[3];  // [2H, H]
  const float* bias = (const float*)d_in[4];  // [2H]
  float* out = (float*)d_out;                 // [B, L, H]

  // ws layout:
  //   [0, 10.5MB)  Afr  (tap fragments; dead after conv)
  //   [0, 16MB)    Wb   (bf16 W; written AFTER conv reads Afr -- same stream)
  //   [16MB, 48MB) Am   (bf16 activations)
  char* ws = (char*)d_ws;
  unsigned short* Afr = (unsigned short*)ws;
  __hip_bfloat16* Wb  = (__hip_bfloat16*)ws;
  unsigned short* Am  = (unsigned short*)(ws + (16 << 20));

  tapfrag_kernel<<<(Hc * 5 * 64) / 256, 256, 0, stream>>>(kin, Afr);
  conv_mfma_kernel<<<dim3(Lc / 512, Hc / 16, Bc), 256, 0, stream>>>(u, Afr, Dp, Am);
  wcast_kernel<<<(2 * Hc * Hc) / 1024, 256, 0, stream>>>(W, Wb);
  gemm_glu_kernel<<<dim3((Bc * Lc / 256) * (Hc / 128)), 512, 0, stream>>>(
      (const __hip_bfloat16*)Am, Wb, bias, out);
}

// Round 3
// 359.491 us; speedup vs baseline: 1.0498x; 1.0002x over previous
//
#include <hip/hip_runtime.h>
#include <hip/hip_bf16.h>
#include <cstdint>

// Problem dims (fixed by reference setup_inputs)
constexpr int Bc  = 2;
constexpr int Lc  = 4096;
constexpr int Hc  = 2048;
constexpr int LKc = 128;
constexpr float LAMc = 0.003f;

typedef __attribute__((ext_vector_type(8))) __bf16 bf16x8;
typedef __attribute__((ext_vector_type(4))) float  f32x4;
typedef __attribute__((ext_vector_type(8))) unsigned short ushort8;

__device__ __forceinline__ unsigned short f2bf_bits(float v) {
  union { __hip_bfloat16 b; unsigned short u; } cv;
  cv.b = __float2bfloat16(v);
  return cv.u;
}
__device__ __forceinline__ float bf_bits2f(unsigned short u) {
  union { unsigned int i; float f; } cv;
  cv.i = ((unsigned int)u) << 16;
  return cv.f;
}

// ---------------------------------------------------------------------------
// async global->LDS, 16B per lane. LDS dest is the WAVE-UNIFORM base; HW adds
// lane*16. Global src is per-lane (pre-gathered fragment order).
// ---------------------------------------------------------------------------
__device__ __forceinline__ void gl_lds16(const void* g, void* lds) {
  __builtin_amdgcn_global_load_lds(
      (const __attribute__((address_space(1))) uint32_t*)(uintptr_t)g,
      (__attribute__((address_space(3))) uint32_t*)(uint32_t)(uintptr_t)lds,
      16, 0, 0);
}

// ---------------------------------------------------------------------------
// Kernel 1: tap squash + Hankel MFMA A-fragment precompute (unchanged).
// ---------------------------------------------------------------------------
__global__ __launch_bounds__(256) void tapfrag_kernel(
    const float* __restrict__ kin, unsigned short* __restrict__ Afr) {
  const int idx  = blockIdx.x * 256 + threadIdx.x;  // [0, 2048*5*64)
  const int lane = idx & 63;
  const int idx2 = idx >> 6;          // h*5 + cc
  const int h  = idx2 / 5;
  const int cc = idx2 - h * 5;
  const int m = lane & 15, quad = lane >> 4;
  const int jb = m + 32 * cc - 32 + 8 * quad;
  ushort8 o;
#pragma unroll
  for (int jj = 0; jj < 8; ++jj) {
    const int j = jb + jj;
    float v = 0.f;
    if (j >= 0 && j < LKc) {
      const float x = kin[h * LKc + j];
      const float a = fabsf(x) - LAMc;
      v = (a > 0.f) ? copysignf(a, x) : 0.f;
    }
    o[jj] = f2bf_bits(v);
  }
  ((ushort8*)Afr)[idx] = o;
}

// ---------------------------------------------------------------------------
// Kernel 2: W fp32 [2H, H] -> bf16 same layout (unchanged).
// ---------------------------------------------------------------------------
__global__ __launch_bounds__(256) void wcast_kernel(
    const float* __restrict__ W, __hip_bfloat16* __restrict__ Wb) {
  const int idx = (blockIdx.x * 256 + threadIdx.x) * 4;
  const float4 v = *(const float4*)(W + idx);
  Wb[idx + 0] = __float2bfloat16(v.x);
  Wb[idx + 1] = __float2bfloat16(v.y);
  Wb[idx + 2] = __float2bfloat16(v.z);
  Wb[idx + 3] = __float2bfloat16(v.w);
}

// ---------------------------------------------------------------------------
// Kernel 3: MFMA FIR conv (unchanged this round).
// ---------------------------------------------------------------------------
__global__ __launch_bounds__(256) void conv_mfma_kernel(
    const float* __restrict__ u, const unsigned short* __restrict__ Afr,
    const float* __restrict__ Dp, unsigned short* __restrict__ Am) {
  __shared__ __align__(16) unsigned short ur[16 * 664];  // 21248 B
  __shared__ __align__(16) unsigned short ot[512 * 17];  // 17408 B

  const int t    = threadIdx.x;
  const int lane = t & 63;
  const int wv   = t >> 6;
  const int l16  = lane & 15;
  const int quad = lane >> 4;
  const int l0 = blockIdx.x * 512;
  const int h0 = blockIdx.y * 16;
  const int b  = blockIdx.z;

  const size_t ubase = (size_t)b * Lc * Hc + h0;

#pragma unroll 4
  for (int i = 0; i < 41; ++i) {
    const int e  = (i << 8) + t;
    const int hl = e & 15;
    const int x  = e >> 4;
    const int l  = l0 + 528 - x;
    float v = 0.f;
    if (l >= 0) v = u[ubase + (size_t)min(l, Lc - 1) * Hc + hl];
    ur[hl * 664 + x] = f2bf_bits(v);
  }
  __syncthreads();

#pragma unroll 1
  for (int hi = 0; hi < 4; ++hi) {
    const int hl = (wv << 2) | hi;
    const int h  = h0 + hl;
    bf16x8 af[5];
    const unsigned short* afp = Afr + ((size_t)(h * 5) * 64 + lane) * 8;
#pragma unroll
    for (int cc = 0; cc < 5; ++cc) af[cc] = *(const bf16x8*)(afp + cc * 512);
    const float dv = 2.f * Dp[h];
    const unsigned short* urh = &ur[hl * 664];
#pragma unroll
    for (int nt = 0; nt < 2; ++nt) {
      f32x4 acc = f32x4{0.f, 0.f, 0.f, 0.f};
      const int bbase = 496 - 256 * nt - 16 * l16 + 8 * quad;
#pragma unroll
      for (int cc = 0; cc < 5; ++cc) {
        const bf16x8 bf = *(const bf16x8*)(urh + bbase + 32 * cc);
        acc = __builtin_amdgcn_mfma_f32_16x16x32_bf16(af[cc], bf, acc, 0, 0, 0);
      }
#pragma unroll
      for (int r = 0; r < 4; ++r) {
        const int lc = quad * 4 + r + 16 * l16;
        const float uu = bf_bits2f(urh[528 - 256 * nt - lc]);
        const float y = fmaf(dv, uu, acc[r]);
        const float g = 0.5f * y * (1.f + erff(y * 0.70710678118654752f));
        ot[(nt * 256 + lc) * 17 + hl] = f2bf_bits(g);
      }
    }
  }
  __syncthreads();

#pragma unroll
  for (int rr = 0; rr < 2; ++rr) {
    const int lc = (rr << 8) + t;
    const unsigned short* row = &ot[lc * 17];
    unsigned int w[8];
#pragma unroll
    for (int p = 0; p < 8; ++p)
      w[p] = (unsigned int)row[2 * p] | ((unsigned int)row[2 * p + 1] << 16);
    unsigned short* dst = Am + ((size_t)(b * Lc + l0 + lc)) * Hc + h0;
    *(uint4*)(dst)     = make_uint4(w[0], w[1], w[2], w[3]);
    *(uint4*)(dst + 8) = make_uint4(w[4], w[5], w[6], w[7]);
  }
}

// ---------------------------------------------------------------------------
// Kernel 4 (v4): relaxed single-barrier GEMM + bias + GLU.
//  - tile 256M x 128N-out (a+g interleaved), 8 waves, BK=32
//  - 4-slot LDS ring (128 KiB), staged 2 K-tiles ahead
//  - ONE s_barrier per K-tile (publication only); staging slot kt+2 never
//    collides with read slots kt/kt+1 -> intra-tile barriers removed
//  - counted s_waitcnt vmcnt(4) boundary wait (never 0 in main loop)
//  - NO sched_barrier pins (r2: regression; compiler schedules interior best)
//  - tile interior: 12 ds_read_b128 || 4 global_load_lds || 32 MFMA,
//    compiler-issued counted lgkmcnt; bfr loaded first (MFMA ready early)
//  - unroll-4 main loop: slot offsets fold to immediates
// ---------------------------------------------------------------------------
constexpr int KTILES = Hc / 32;  // 64

__global__ __launch_bounds__(512, 2) void gemm_glu_kernel(
    const __hip_bfloat16* __restrict__ A, const __hip_bfloat16* __restrict__ Wb,
    const float* __restrict__ bias, float* __restrict__ out) {
  __shared__ __align__(16) char lds[131072];  // 4 slots x (A 16KB + B 16KB)

  const int t    = threadIdx.x;
  const int lane = t & 63;
  const int w    = t >> 6;        // wave 0..7
  const int l16  = lane & 15;
  const int quad = lane >> 4;
  const int wr   = w >> 2;        // 0..1 : M band
  const int wc   = w & 3;         // 0..3 : N band

  const int bid = blockIdx.x;                   // 0..511
  const int wg  = (bid & 7) * 64 + (bid >> 3);  // XCD swizzle (512 % 8 == 0)
  const int m0g = (wg & 31) * 256;
  const int n0  = (wg >> 5) * 128;

  // per-thread pre-gathered staging sources: idx 0,1 = A units, 2,3 = B units
  const __hip_bfloat16* gsrc[4];
#pragma unroll
  for (int u = 0; u < 2; ++u) {
    const int f = u * 8 + w;  // fragment index 0..15 staged by this wave
    gsrc[u] = A + (size_t)(m0g + f * 16 + l16) * Hc + quad * 8;
    const int wrow = ((f >> 1) & 1) * Hc + n0 + (f >> 2) * 32 + (f & 1) * 16 + l16;
    gsrc[2 + u] = Wb + (size_t)wrow * Hc + quad * 8;
  }

  f32x4 acc[8][4];
#pragma unroll
  for (int i = 0; i < 8; ++i)
#pragma unroll
    for (int j = 0; j < 4; ++j) acc[i][j] = f32x4{0.f, 0.f, 0.f, 0.f};

// wave-uniform LDS dest: slot + region + frag run; HW adds lane*16
#define STAGE(tile, idx)                                                      \
  gl_lds16(gsrc[idx] + (size_t)(tile) * 32,                                   \
           lds + ((tile) & 3) * 32768 + (((idx) >> 1) & 1) * 16384 +          \
               (((idx) & 1) * 8 + w) * 1024)

  // prologue: K-tiles 0 and 1 (4 loads/lane each)
#pragma unroll
  for (int i = 0; i < 4; ++i) STAGE(0, i);
#pragma unroll
  for (int i = 0; i < 4; ++i) STAGE(1, i);
  asm volatile("s_waitcnt vmcnt(4)" ::: "memory");  // tile 0 landed
  __builtin_amdgcn_s_barrier();

  const char* sAbase = lds + wr * 8192 + lane * 16;
  const char* sBbase = lds + 16384 + wc * 4096 + lane * 16;

  // One BK=32 K-tile: {12 ds_read || 4 stage || 32 MFMA} -> vmcnt(N) -> barrier
#define KTILE_BODY(KT, DO_STAGE, VMN)                                         \
  {                                                                           \
    const char* sA = sAbase + ((KT) & 3) * 32768;                             \
    const char* sB = sBbase + ((KT) & 3) * 32768;                             \
    bf16x8 afr[8], bfr[4];                                                    \
    _Pragma("unroll") for (int i = 0; i < 4; ++i)                             \
        bfr[i] = *(const bf16x8*)(sB + i * 1024);                             \
    _Pragma("unroll") for (int i = 0; i < 8; ++i)                             \
        afr[i] = *(const bf16x8*)(sA + i * 1024);                             \
    if (DO_STAGE) {                                                           \
      STAGE((KT) + 2, 0); STAGE((KT) + 2, 1);                                 \
      STAGE((KT) + 2, 2); STAGE((KT) + 2, 3);                                 \
    }                                                                         \
    __builtin_amdgcn_s_setprio(1);                                            \
    _Pragma("unroll") for (int mf = 0; mf < 8; ++mf)                          \
        _Pragma("unroll") for (int nf = 0; nf < 4; ++nf)                      \
            acc[mf][nf] = __builtin_amdgcn_mfma_f32_16x16x32_bf16(            \
                afr[mf], bfr[nf], acc[mf][nf], 0, 0, 0);                      \
    __builtin_amdgcn_s_setprio(0);                                            \
    asm volatile("s_waitcnt vmcnt(" #VMN ")" ::: "memory");                   \
    __builtin_amdgcn_s_barrier();                                             \
  }

  // main loop: tiles 0..59 (unroll 4 folds slot offsets), staging kt+2
#pragma unroll 1
  for (int k4 = 0; k4 < 15; ++k4) {
    const int kt = k4 * 4;
    KTILE_BODY(kt + 0, true, 4)
    KTILE_BODY(kt + 1, true, 4)
    KTILE_BODY(kt + 2, true, 4)
    KTILE_BODY(kt + 3, true, 4)
  }
  // tail: tiles 60,61 still stage (62,63); 62,63 drain
  KTILE_BODY(60, true, 4)
  KTILE_BODY(61, true, 4)
  KTILE_BODY(62, false, 0)
  KTILE_BODY(63, false, 0)
#undef KTILE_BODY
#undef STAGE

  // ---------- epilogue: lane-local GLU (a at nf, g at nf+2), coalesced rows
  const int mwb = m0g + wr * 128 + quad * 4;
  const int nb  = n0 + wc * 32 + l16;
#pragma unroll
  for (int j = 0; j < 2; ++j) {
    const int n = nb + j * 16;
    const float ba = bias[n];
    const float bg = bias[Hc + n];
#pragma unroll
    for (int mf = 0; mf < 8; ++mf) {
#pragma unroll
      for (int r = 0; r < 4; ++r) {
        const float a = acc[mf][j][r] + ba;
        const float g = acc[mf][j + 2][r] + bg;
        out[(size_t)(mwb + mf * 16 + r) * Hc + n] = a * (1.f / (1.f + expf(-g)));
      }
    }
  }
}

// ---------------------------------------------------------------------------
extern "C" void kernel_launch(void* const* d_in, const int* in_sizes, int n_in,
                              void* d_out, int out_size, void* d_ws, size_t ws_size,
                              hipStream_t stream) {
  const float* u    = (const float*)d_in[0];  // [B, L, H]
  const float* kin  = (const float*)d_in[1];  // [1, H, LK]
  const float* Dp   = (const float*)d_in[2];  // [1, H]
  const float* W    = (const float*)d_in[3];  // [2H, H]
  const float* bias = (const float*)d_in[4];  // [2H]
  float* out = (float*)d_out;                 // [B, L, H]

  // ws layout:
  //   [0, 10.5MB)  Afr  (tap fragments; dead after conv)
  //   [0, 16MB)    Wb   (bf16 W; written AFTER conv reads Afr -- same stream)
  //   [16MB, 48MB) Am   (bf16 activations)
  char* ws = (char*)d_ws;
  unsigned short* Afr = (unsigned short*)ws;
  __hip_bfloat16* Wb  = (__hip_bfloat16*)ws;
  unsigned short* Am  = (unsigned short*)(ws + (16 << 20));

  tapfrag_kernel<<<(Hc * 5 * 64) / 256, 256, 0, stream>>>(kin, Afr);
  conv_mfma_kernel<<<dim3(Lc / 512, Hc / 16, Bc), 256, 0, stream>>>(u, Afr, Dp, Am);
  wcast_kernel<<<(2 * Hc * Hc) / 1024, 256, 0, stream>>>(W, Wb);
  gemm_glu_kernel<<<dim3((Bc * Lc / 256) * (Hc / 128)), 512, 0, stream>>>(
      (const __hip_bfloat16*)Am, Wb, bias, out);
}

// Round 5
// 350.190 us; speedup vs baseline: 1.0777x; 1.0266x over previous
//
#include <hip/hip_runtime.h>
#include <hip/hip_bf16.h>
#include <cstdint>

// Problem dims (fixed by reference setup_inputs)
constexpr int Bc  = 2;
constexpr int Lc  = 4096;
constexpr int Hc  = 2048;
constexpr int LKc = 128;
constexpr float LAMc = 0.003f;

typedef __attribute__((ext_vector_type(8))) __bf16 bf16x8;
typedef __attribute__((ext_vector_type(4))) float  f32x4;
typedef __attribute__((ext_vector_type(8))) unsigned short ushort8;

__device__ __forceinline__ unsigned short f2bf_bits(float v) {
  union { __hip_bfloat16 b; unsigned short u; } cv;
  cv.b = __float2bfloat16(v);
  return cv.u;
}
__device__ __forceinline__ float bf_bits2f(unsigned short u) {
  union { unsigned int i; float f; } cv;
  cv.i = ((unsigned int)u) << 16;
  return cv.f;
}

// ---------------------------------------------------------------------------
// async global->LDS, 16B per lane. LDS dest is the WAVE-UNIFORM base; HW adds
// lane*16. Global src is per-lane (pre-gathered fragment order).
// ---------------------------------------------------------------------------
__device__ __forceinline__ void gl_lds16(const void* g, void* lds) {
  __builtin_amdgcn_global_load_lds(
      (const __attribute__((address_space(1))) uint32_t*)(uintptr_t)g,
      (__attribute__((address_space(3))) uint32_t*)(uint32_t)(uintptr_t)lds,
      16, 0, 0);
}

// ---------------------------------------------------------------------------
// Kernel 1: tap squash + Hankel MFMA A-fragment precompute (unchanged).
// ---------------------------------------------------------------------------
__global__ __launch_bounds__(256) void tapfrag_kernel(
    const float* __restrict__ kin, unsigned short* __restrict__ Afr) {
  const int idx  = blockIdx.x * 256 + threadIdx.x;  // [0, 2048*5*64)
  const int lane = idx & 63;
  const int idx2 = idx >> 6;          // h*5 + cc
  const int h  = idx2 / 5;
  const int cc = idx2 - h * 5;
  const int m = lane & 15, quad = lane >> 4;
  const int jb = m + 32 * cc - 32 + 8 * quad;
  ushort8 o;
#pragma unroll
  for (int jj = 0; jj < 8; ++jj) {
    const int j = jb + jj;
    float v = 0.f;
    if (j >= 0 && j < LKc) {
      const float x = kin[h * LKc + j];
      const float a = fabsf(x) - LAMc;
      v = (a > 0.f) ? copysignf(a, x) : 0.f;
    }
    o[jj] = f2bf_bits(v);
  }
  ((ushort8*)Afr)[idx] = o;
}

// ---------------------------------------------------------------------------
// Kernel 2: W fp32 [2H, H] -> bf16 same layout (unchanged).
// ---------------------------------------------------------------------------
__global__ __launch_bounds__(256) void wcast_kernel(
    const float* __restrict__ W, __hip_bfloat16* __restrict__ Wb) {
  const int idx = (blockIdx.x * 256 + threadIdx.x) * 4;
  const float4 v = *(const float4*)(W + idx);
  Wb[idx + 0] = __float2bfloat16(v.x);
  Wb[idx + 1] = __float2bfloat16(v.y);
  Wb[idx + 2] = __float2bfloat16(v.z);
  Wb[idx + 3] = __float2bfloat16(v.w);
}

// ---------------------------------------------------------------------------
// Kernel 3: MFMA FIR conv (unchanged this round).
// ---------------------------------------------------------------------------
__global__ __launch_bounds__(256) void conv_mfma_kernel(
    const float* __restrict__ u, const unsigned short* __restrict__ Afr,
    const float* __restrict__ Dp, unsigned short* __restrict__ Am) {
  __shared__ __align__(16) unsigned short ur[16 * 664];  // 21248 B
  __shared__ __align__(16) unsigned short ot[512 * 17];  // 17408 B

  const int t    = threadIdx.x;
  const int lane = t & 63;
  const int wv   = t >> 6;
  const int l16  = lane & 15;
  const int quad = lane >> 4;
  const int l0 = blockIdx.x * 512;
  const int h0 = blockIdx.y * 16;
  const int b  = blockIdx.z;

  const size_t ubase = (size_t)b * Lc * Hc + h0;

#pragma unroll 4
  for (int i = 0; i < 41; ++i) {
    const int e  = (i << 8) + t;
    const int hl = e & 15;
    const int x  = e >> 4;
    const int l  = l0 + 528 - x;
    float v = 0.f;
    if (l >= 0) v = u[ubase + (size_t)min(l, Lc - 1) * Hc + hl];
    ur[hl * 664 + x] = f2bf_bits(v);
  }
  __syncthreads();

#pragma unroll 1
  for (int hi = 0; hi < 4; ++hi) {
    const int hl = (wv << 2) | hi;
    const int h  = h0 + hl;
    bf16x8 af[5];
    const unsigned short* afp = Afr + ((size_t)(h * 5) * 64 + lane) * 8;
#pragma unroll
    for (int cc = 0; cc < 5; ++cc) af[cc] = *(const bf16x8*)(afp + cc * 512);
    const float dv = 2.f * Dp[h];
    const unsigned short* urh = &ur[hl * 664];
#pragma unroll
    for (int nt = 0; nt < 2; ++nt) {
      f32x4 acc = f32x4{0.f, 0.f, 0.f, 0.f};
      const int bbase = 496 - 256 * nt - 16 * l16 + 8 * quad;
#pragma unroll
      for (int cc = 0; cc < 5; ++cc) {
        const bf16x8 bf = *(const bf16x8*)(urh + bbase + 32 * cc);
        acc = __builtin_amdgcn_mfma_f32_16x16x32_bf16(af[cc], bf, acc, 0, 0, 0);
      }
#pragma unroll
      for (int r = 0; r < 4; ++r) {
        const int lc = quad * 4 + r + 16 * l16;
        const float uu = bf_bits2f(urh[528 - 256 * nt - lc]);
        const float y = fmaf(dv, uu, acc[r]);
        const float g = 0.5f * y * (1.f + erff(y * 0.70710678118654752f));
        ot[(nt * 256 + lc) * 17 + hl] = f2bf_bits(g);
      }
    }
  }
  __syncthreads();

#pragma unroll
  for (int rr = 0; rr < 2; ++rr) {
    const int lc = (rr << 8) + t;
    const unsigned short* row = &ot[lc * 17];
    unsigned int w[8];
#pragma unroll
    for (int p = 0; p < 8; ++p)
      w[p] = (unsigned int)row[2 * p] | ((unsigned int)row[2 * p + 1] << 16);
    unsigned short* dst = Am + ((size_t)(b * Lc + l0 + lc)) * Hc + h0;
    *(uint4*)(dst)     = make_uint4(w[0], w[1], w[2], w[3]);
    *(uint4*)(dst + 8) = make_uint4(w[4], w[5], w[6], w[7]);
  }
}

// ---------------------------------------------------------------------------
// Kernel 4 (v5, resubmit): latency-tolerant GEMM + bias + GLU.
//  - tile 256M x 128N-out (a+g interleaved), 8 waves, BK=32
//  - 4-slot LDS ring; staged THREE K-tiles ahead. Read slot kt&3, stage
//    (kt+3)&3 = slot whose reads finished one barrier ago (race-free: stage
//    issue is post-barrier; that slot's readers completed pre-barrier).
//    Boundary wait vmcnt(8): loads get 3 tiles of flight time ->
//    tile clock = max(compute, latency/3), was latency/2.
//  - L2-locality remap: each XCD owns 2 concurrent A m-panels (2MB,
//    L2-resident, 16x reuse) x 16 W n-panels (2x L2 + 8x L3 reuse).
//  - one s_barrier per K-tile (r3: barrier count is not the bottleneck)
//  - fragment-packed LDS -> 0 bank conflicts (r1-verified)
// ---------------------------------------------------------------------------
constexpr int KTILES = Hc / 32;  // 64

__global__ __launch_bounds__(512, 2) void gemm_glu_kernel(
    const __hip_bfloat16* __restrict__ A, const __hip_bfloat16* __restrict__ Wb,
    const float* __restrict__ bias, float* __restrict__ out) {
  __shared__ __align__(16) char lds[131072];  // 4 slots x (A 16KB + B 16KB)

  const int t    = threadIdx.x;
  const int lane = t & 63;
  const int w    = t >> 6;        // wave 0..7
  const int l16  = lane & 15;
  const int quad = lane >> 4;
  const int wr   = w >> 2;        // 0..1 : M band
  const int wc   = w & 3;         // 0..3 : N band

  // bijective XCD-locality remap: xcd = bid&7 (HW round-robin), s = bid>>3.
  // m_blk = xcd*4 + (s>>4) in [0,32), n_blk = s&15 in [0,16).
  const int bid = blockIdx.x;     // 0..511
  const int xcd = bid & 7;
  const int s   = bid >> 3;       // 0..63
  const int m0g = (xcd * 4 + (s >> 4)) * 256;
  const int n0  = (s & 15) * 128;

  // per-thread pre-gathered staging sources: idx 0,1 = A units, 2,3 = B units
  const __hip_bfloat16* gsrc[4];
#pragma unroll
  for (int u = 0; u < 2; ++u) {
    const int f = u * 8 + w;  // fragment index 0..15 staged by this wave
    gsrc[u] = A + (size_t)(m0g + f * 16 + l16) * Hc + quad * 8;
    const int wrow = ((f >> 1) & 1) * Hc + n0 + (f >> 2) * 32 + (f & 1) * 16 + l16;
    gsrc[2 + u] = Wb + (size_t)wrow * Hc + quad * 8;
  }

  f32x4 acc[8][4];
#pragma unroll
  for (int i = 0; i < 8; ++i)
#pragma unroll
    for (int j = 0; j < 4; ++j) acc[i][j] = f32x4{0.f, 0.f, 0.f, 0.f};

// wave-uniform LDS dest: slot + region + frag run; HW adds lane*16
#define STAGE(tile, idx)                                                      \
  gl_lds16(gsrc[idx] + (size_t)(tile) * 32,                                   \
           lds + ((tile) & 3) * 32768 + (((idx) >> 1) & 1) * 16384 +          \
               (((idx) & 1) * 8 + w) * 1024)

  // prologue: K-tiles 0,1,2 (4 loads/lane each, 12 outstanding)
#pragma unroll
  for (int i = 0; i < 4; ++i) STAGE(0, i);
#pragma unroll
  for (int i = 0; i < 4; ++i) STAGE(1, i);
#pragma unroll
  for (int i = 0; i < 4; ++i) STAGE(2, i);
  asm volatile("s_waitcnt vmcnt(8)" ::: "memory");  // tile 0 landed
  __builtin_amdgcn_s_barrier();

  const char* sAbase = lds + wr * 8192 + lane * 16;
  const char* sBbase = lds + 16384 + wc * 4096 + lane * 16;

  // One BK=32 K-tile: {12 ds_read || 4 stage(kt+3) || 32 MFMA} -> vmcnt(N)
  // -> barrier.  Steady-state VMN=8 (tiles kt+2,kt+3 in flight; kt+1 landed).
#define KTILE_BODY(KT, DO_STAGE, VMN)                                         \
  {                                                                           \
    const char* sA = sAbase + ((KT) & 3) * 32768;                             \
    const char* sB = sBbase + ((KT) & 3) * 32768;                             \
    bf16x8 afr[8], bfr[4];                                                    \
    _Pragma("unroll") for (int i = 0; i < 4; ++i)                             \
        bfr[i] = *(const bf16x8*)(sB + i * 1024);                             \
    _Pragma("unroll") for (int i = 0; i < 8; ++i)                             \
        afr[i] = *(const bf16x8*)(sA + i * 1024);                             \
    if (DO_STAGE) {                                                           \
      STAGE((KT) + 3, 0); STAGE((KT) + 3, 1);                                 \
      STAGE((KT) + 3, 2); STAGE((KT) + 3, 3);                                 \
    }                                                                         \
    __builtin_amdgcn_s_setprio(1);                                            \
    _Pragma("unroll") for (int mf = 0; mf < 8; ++mf)                          \
        _Pragma("unroll") for (int nf = 0; nf < 4; ++nf)                      \
            acc[mf][nf] = __builtin_amdgcn_mfma_f32_16x16x32_bf16(            \
                afr[mf], bfr[nf], acc[mf][nf], 0, 0, 0);                      \
    __builtin_amdgcn_s_setprio(0);                                            \
    asm volatile("s_waitcnt vmcnt(" #VMN ")" ::: "memory");                   \
    __builtin_amdgcn_s_barrier();                                             \
  }

  // main loop: tiles 0..59 (unroll 4 folds slot offsets), staging kt+3
#pragma unroll 1
  for (int k4 = 0; k4 < 15; ++k4) {
    const int kt = k4 * 4;
    KTILE_BODY(kt + 0, true, 8)
    KTILE_BODY(kt + 1, true, 8)
    KTILE_BODY(kt + 2, true, 8)
    KTILE_BODY(kt + 3, true, 8)
  }
  // tail: tile 60 stages 63 (last); then drain 8 -> 4 -> 0
  KTILE_BODY(60, true, 8)
  KTILE_BODY(61, false, 4)
  KTILE_BODY(62, false, 0)
  KTILE_BODY(63, false, 0)
#undef KTILE_BODY
#undef STAGE

  // ---------- epilogue: lane-local GLU (a at nf, g at nf+2), coalesced rows
  const int mwb = m0g + wr * 128 + quad * 4;
  const int nb  = n0 + wc * 32 + l16;
#pragma unroll
  for (int j = 0; j < 2; ++j) {
    const int n = nb + j * 16;
    const float ba = bias[n];
    const float bg = bias[Hc + n];
#pragma unroll
    for (int mf = 0; mf < 8; ++mf) {
#pragma unroll
      for (int r = 0; r < 4; ++r) {
        const float a = acc[mf][j][r] + ba;
        const float g = acc[mf][j + 2][r] + bg;
        out[(size_t)(mwb + mf * 16 + r) * Hc + n] = a * (1.f / (1.f + expf(-g)));
      }
    }
  }
}

// ---------------------------------------------------------------------------
extern "C" void kernel_launch(void* const* d_in, const int* in_sizes, int n_in,
                              void* d_out, int out_size, void* d_ws, size_t ws_size,
                              hipStream_t stream) {
  const float* u    = (const float*)d_in[0];  // [B, L, H]
  const float* kin  = (const float*)d_in[1];  // [1, H, LK]
  const float* Dp   = (const float*)d_in[2];  // [1, H]
  const float* W    = (const float*)d_in[3];  // [2H, H]
  const float* bias = (const float*)d_in[4];  // [2H]
  float* out = (float*)d_out;                 // [B, L, H]

  // ws layout:
  //   [0, 10.5MB)  Afr  (tap fragments; dead after conv)
  //   [0, 16MB)    Wb   (bf16 W; written AFTER conv reads Afr -- same stream)
  //   [16MB, 48MB) Am   (bf16 activations)
  char* ws = (char*)d_ws;
  unsigned short* Afr = (unsigned short*)ws;
  __hip_bfloat16* Wb  = (__hip_bfloat16*)ws;
  unsigned short* Am  = (unsigned short*)(ws + (16 << 20));

  tapfrag_kernel<<<(Hc * 5 * 64) / 256, 256, 0, stream>>>(kin, Afr);
  conv_mfma_kernel<<<dim3(Lc / 512, Hc / 16, Bc), 256, 0, stream>>>(u, Afr, Dp, Am);
  wcast_kernel<<<(2 * Hc * Hc) / 1024, 256, 0, stream>>>(W, Wb);
  gemm_glu_kernel<<<dim3((Bc * Lc / 256) * (Hc / 128)), 512, 0, stream>>>(
      (const __hip_bfloat16*)Am, Wb, bias, out);
}

// Round 6
// 326.195 us; speedup vs baseline: 1.1570x; 1.0736x over previous
//
#include <hip/hip_runtime.h>
#include <hip/hip_bf16.h>
#include <cstdint>

// Problem dims (fixed by reference setup_inputs)
constexpr int Bc  = 2;
constexpr int Lc  = 4096;
constexpr int Hc  = 2048;
constexpr int LKc = 128;
constexpr float LAMc = 0.003f;

typedef __attribute__((ext_vector_type(8))) __bf16 bf16x8;
typedef __attribute__((ext_vector_type(4))) float  f32x4;
typedef __attribute__((ext_vector_type(8))) unsigned short ushort8;

__device__ __forceinline__ unsigned short f2bf_bits(float v) {
  union { __hip_bfloat16 b; unsigned short u; } cv;
  cv.b = __float2bfloat16(v);
  return cv.u;
}
__device__ __forceinline__ float bf_bits2f(unsigned short u) {
  union { unsigned int i; float f; } cv;
  cv.i = ((unsigned int)u) << 16;
  return cv.f;
}

// ---------------------------------------------------------------------------
// async global->LDS, 16B per lane. LDS dest is the WAVE-UNIFORM base; HW adds
// lane*16. Global src is per-lane (pre-gathered fragment order).
// ---------------------------------------------------------------------------
__device__ __forceinline__ void gl_lds16(const void* g, void* lds) {
  __builtin_amdgcn_global_load_lds(
      (const __attribute__((address_space(1))) uint32_t*)(uintptr_t)g,
      (__attribute__((address_space(3))) uint32_t*)(uint32_t)(uintptr_t)lds,
      16, 0, 0);
}

// ---------------------------------------------------------------------------
// Kernel 1: tap squash + Hankel MFMA A-fragment precompute (unchanged).
// ---------------------------------------------------------------------------
__global__ __launch_bounds__(256) void tapfrag_kernel(
    const float* __restrict__ kin, unsigned short* __restrict__ Afr) {
  const int idx  = blockIdx.x * 256 + threadIdx.x;  // [0, 2048*5*64)
  const int lane = idx & 63;
  const int idx2 = idx >> 6;          // h*5 + cc
  const int h  = idx2 / 5;
  const int cc = idx2 - h * 5;
  const int m = lane & 15, quad = lane >> 4;
  const int jb = m + 32 * cc - 32 + 8 * quad;
  ushort8 o;
#pragma unroll
  for (int jj = 0; jj < 8; ++jj) {
    const int j = jb + jj;
    float v = 0.f;
    if (j >= 0 && j < LKc) {
      const float x = kin[h * LKc + j];
      const float a = fabsf(x) - LAMc;
      v = (a > 0.f) ? copysignf(a, x) : 0.f;
    }
    o[jj] = f2bf_bits(v);
  }
  ((ushort8*)Afr)[idx] = o;
}

// ---------------------------------------------------------------------------
// Kernel 2: W fp32 [2H, H] -> bf16 same layout (unchanged).
// ---------------------------------------------------------------------------
__global__ __launch_bounds__(256) void wcast_kernel(
    const float* __restrict__ W, __hip_bfloat16* __restrict__ Wb) {
  const int idx = (blockIdx.x * 256 + threadIdx.x) * 4;
  const float4 v = *(const float4*)(W + idx);
  Wb[idx + 0] = __float2bfloat16(v.x);
  Wb[idx + 1] = __float2bfloat16(v.y);
  Wb[idx + 2] = __float2bfloat16(v.z);
  Wb[idx + 3] = __float2bfloat16(v.w);
}

// ---------------------------------------------------------------------------
// Kernel 3 (v2): MFMA FIR conv; staging vectorized to float4 (4 h per lane).
//  - 41 scalar loads/thread -> 11 float4 loads/thread (4x fewer vmem instr,
//    4x fewer address computations); all Hankel/MFMA index math unchanged.
// ---------------------------------------------------------------------------
__global__ __launch_bounds__(256) void conv_mfma_kernel(
    const float* __restrict__ u, const unsigned short* __restrict__ Afr,
    const float* __restrict__ Dp, unsigned short* __restrict__ Am) {
  __shared__ __align__(16) unsigned short ur[16 * 664];  // 21248 B
  __shared__ __align__(16) unsigned short ot[512 * 17];  // 17408 B

  const int t    = threadIdx.x;
  const int lane = t & 63;
  const int wv   = t >> 6;
  const int l16  = lane & 15;
  const int quad = lane >> 4;
  const int l0 = blockIdx.x * 512;
  const int h0 = blockIdx.y * 16;
  const int b  = blockIdx.z;

  const size_t ubase = (size_t)b * Lc * Hc + h0;

  // ---- stage 16 h x 656 l (reversed, bf16) via float4: 2624 units, 11 iters
#pragma unroll
  for (int i = 0; i < 11; ++i) {
    const int e = i * 256 + t;
    if (e < 2624) {
      const int x  = e >> 2;          // 0..655
      const int hq = (e & 3) << 2;    // 0,4,8,12
      const int l  = l0 + 528 - x;
      float4 v = make_float4(0.f, 0.f, 0.f, 0.f);
      if (l >= 0)
        v = *(const float4*)(u + ubase + (size_t)min(l, Lc - 1) * Hc + hq);
      ur[(hq + 0) * 664 + x] = f2bf_bits(v.x);
      ur[(hq + 1) * 664 + x] = f2bf_bits(v.y);
      ur[(hq + 2) * 664 + x] = f2bf_bits(v.z);
      ur[(hq + 3) * 664 + x] = f2bf_bits(v.w);
    }
  }
  __syncthreads();

#pragma unroll 1
  for (int hi = 0; hi < 4; ++hi) {
    const int hl = (wv << 2) | hi;
    const int h  = h0 + hl;
    bf16x8 af[5];
    const unsigned short* afp = Afr + ((size_t)(h * 5) * 64 + lane) * 8;
#pragma unroll
    for (int cc = 0; cc < 5; ++cc) af[cc] = *(const bf16x8*)(afp + cc * 512);
    const float dv = 2.f * Dp[h];
    const unsigned short* urh = &ur[hl * 664];
#pragma unroll
    for (int nt = 0; nt < 2; ++nt) {
      f32x4 acc = f32x4{0.f, 0.f, 0.f, 0.f};
      const int bbase = 496 - 256 * nt - 16 * l16 + 8 * quad;
#pragma unroll
      for (int cc = 0; cc < 5; ++cc) {
        const bf16x8 bf = *(const bf16x8*)(urh + bbase + 32 * cc);
        acc = __builtin_amdgcn_mfma_f32_16x16x32_bf16(af[cc], bf, acc, 0, 0, 0);
      }
#pragma unroll
      for (int r = 0; r < 4; ++r) {
        const int lc = quad * 4 + r + 16 * l16;
        const float uu = bf_bits2f(urh[528 - 256 * nt - lc]);
        const float y = fmaf(dv, uu, acc[r]);
        const float g = 0.5f * y * (1.f + erff(y * 0.70710678118654752f));
        ot[(nt * 256 + lc) * 17 + hl] = f2bf_bits(g);
      }
    }
  }
  __syncthreads();

#pragma unroll
  for (int rr = 0; rr < 2; ++rr) {
    const int lc = (rr << 8) + t;
    const unsigned short* row = &ot[lc * 17];
    unsigned int w[8];
#pragma unroll
    for (int p = 0; p < 8; ++p)
      w[p] = (unsigned int)row[2 * p] | ((unsigned int)row[2 * p + 1] << 16);
    unsigned short* dst = Am + ((size_t)(b * Lc + l0 + lc)) * Hc + h0;
    *(uint4*)(dst)     = make_uint4(w[0], w[1], w[2], w[3]);
    *(uint4*)(dst + 8) = make_uint4(w[4], w[5], w[6], w[7]);
  }
}

// ---------------------------------------------------------------------------
// Kernel 4 (v5, FROZEN): latency-tolerant GEMM + bias + GLU.
//  - 4-slot LDS ring, staged 3 K-tiles ahead, vmcnt(8) boundary wait
//  - L2-locality XCD remap (FETCH 270->148 MB verified r5)
//  - fragment-packed LDS -> 0 bank conflicts (r1-verified)
// ---------------------------------------------------------------------------
constexpr int KTILES = Hc / 32;  // 64

__global__ __launch_bounds__(512, 2) void gemm_glu_kernel(
    const __hip_bfloat16* __restrict__ A, const __hip_bfloat16* __restrict__ Wb,
    const float* __restrict__ bias, float* __restrict__ out) {
  __shared__ __align__(16) char lds[131072];  // 4 slots x (A 16KB + B 16KB)

  const int t    = threadIdx.x;
  const int lane = t & 63;
  const int w    = t >> 6;        // wave 0..7
  const int l16  = lane & 15;
  const int quad = lane >> 4;
  const int wr   = w >> 2;        // 0..1 : M band
  const int wc   = w & 3;         // 0..3 : N band

  // bijective XCD-locality remap: xcd = bid&7 (HW round-robin), s = bid>>3.
  const int bid = blockIdx.x;     // 0..511
  const int xcd = bid & 7;
  const int s   = bid >> 3;       // 0..63
  const int m0g = (xcd * 4 + (s >> 4)) * 256;
  const int n0  = (s & 15) * 128;

  // per-thread pre-gathered staging sources: idx 0,1 = A units, 2,3 = B units
  const __hip_bfloat16* gsrc[4];
#pragma unroll
  for (int u = 0; u < 2; ++u) {
    const int f = u * 8 + w;  // fragment index 0..15 staged by this wave
    gsrc[u] = A + (size_t)(m0g + f * 16 + l16) * Hc + quad * 8;
    const int wrow = ((f >> 1) & 1) * Hc + n0 + (f >> 2) * 32 + (f & 1) * 16 + l16;
    gsrc[2 + u] = Wb + (size_t)wrow * Hc + quad * 8;
  }

  f32x4 acc[8][4];
#pragma unroll
  for (int i = 0; i < 8; ++i)
#pragma unroll
    for (int j = 0; j < 4; ++j) acc[i][j] = f32x4{0.f, 0.f, 0.f, 0.f};

// wave-uniform LDS dest: slot + region + frag run; HW adds lane*16
#define STAGE(tile, idx)                                                      \
  gl_lds16(gsrc[idx] + (size_t)(tile) * 32,                                   \
           lds + ((tile) & 3) * 32768 + (((idx) >> 1) & 1) * 16384 +          \
               (((idx) & 1) * 8 + w) * 1024)

  // prologue: K-tiles 0,1,2 (4 loads/lane each, 12 outstanding)
#pragma unroll
  for (int i = 0; i < 4; ++i) STAGE(0, i);
#pragma unroll
  for (int i = 0; i < 4; ++i) STAGE(1, i);
#pragma unroll
  for (int i = 0; i < 4; ++i) STAGE(2, i);
  asm volatile("s_waitcnt vmcnt(8)" ::: "memory");  // tile 0 landed
  __builtin_amdgcn_s_barrier();

  const char* sAbase = lds + wr * 8192 + lane * 16;
  const char* sBbase = lds + 16384 + wc * 4096 + lane * 16;

  // One BK=32 K-tile: {12 ds_read || 4 stage(kt+3) || 32 MFMA} -> vmcnt(N)
  // -> barrier.  Steady-state VMN=8 (tiles kt+2,kt+3 in flight; kt+1 landed).
#define KTILE_BODY(KT, DO_STAGE, VMN)                                         \
  {                                                                           \
    const char* sA = sAbase + ((KT) & 3) * 32768;                             \
    const char* sB = sBbase + ((KT) & 3) * 32768;                             \
    bf16x8 afr[8], bfr[4];                                                    \
    _Pragma("unroll") for (int i = 0; i < 4; ++i)                             \
        bfr[i] = *(const bf16x8*)(sB + i * 1024);                             \
    _Pragma("unroll") for (int i = 0; i < 8; ++i)                             \
        afr[i] = *(const bf16x8*)(sA + i * 1024);                             \
    if (DO_STAGE) {                                                           \
      STAGE((KT) + 3, 0); STAGE((KT) + 3, 1);                                 \
      STAGE((KT) + 3, 2); STAGE((KT) + 3, 3);                                 \
    }                                                                         \
    __builtin_amdgcn_s_setprio(1);                                            \
    _Pragma("unroll") for (int mf = 0; mf < 8; ++mf)                          \
        _Pragma("unroll") for (int nf = 0; nf < 4; ++nf)                      \
            acc[mf][nf] = __builtin_amdgcn_mfma_f32_16x16x32_bf16(            \
                afr[mf], bfr[nf], acc[mf][nf], 0, 0, 0);                      \
    __builtin_amdgcn_s_setprio(0);                                            \
    asm volatile("s_waitcnt vmcnt(" #VMN ")" ::: "memory");                   \
    __builtin_amdgcn_s_barrier();                                             \
  }

  // main loop: tiles 0..59 (unroll 4 folds slot offsets), staging kt+3
#pragma unroll 1
  for (int k4 = 0; k4 < 15; ++k4) {
    const int kt = k4 * 4;
    KTILE_BODY(kt + 0, true, 8)
    KTILE_BODY(kt + 1, true, 8)
    KTILE_BODY(kt + 2, true, 8)
    KTILE_BODY(kt + 3, true, 8)
  }
  // tail: tile 60 stages 63 (last); then drain 8 -> 4 -> 0
  KTILE_BODY(60, true, 8)
  KTILE_BODY(61, false, 4)
  KTILE_BODY(62, false, 0)
  KTILE_BODY(63, false, 0)
#undef KTILE_BODY
#undef STAGE

  // ---------- epilogue: lane-local GLU (a at nf, g at nf+2), coalesced rows
  const int mwb = m0g + wr * 128 + quad * 4;
  const int nb  = n0 + wc * 32 + l16;
#pragma unroll
  for (int j = 0; j < 2; ++j) {
    const int n = nb + j * 16;
    const float ba = bias[n];
    const float bg = bias[Hc + n];
#pragma unroll
    for (int mf = 0; mf < 8; ++mf) {
#pragma unroll
      for (int r = 0; r < 4; ++r) {
        const float a = acc[mf][j][r] + ba;
        const float g = acc[mf][j + 2][r] + bg;
        out[(size_t)(mwb + mf * 16 + r) * Hc + n] = a * (1.f / (1.f + expf(-g)));
      }
    }
  }
}

// ---------------------------------------------------------------------------
extern "C" void kernel_launch(void* const* d_in, const int* in_sizes, int n_in,
                              void* d_out, int out_size, void* d_ws, size_t ws_size,
                              hipStream_t stream) {
  const float* u    = (const float*)d_in[0];  // [B, L, H]
  const float* kin  = (const float*)d_in[1];  // [1, H, LK]
  const float* Dp   = (const float*)d_in[2];  // [1, H]
  const float* W    = (const float*)d_in[3];  // [2H, H]
  const float* bias = (const float*)d_in[4];  // [2H]
  float* out = (float*)d_out;                 // [B, L, H]

  // ws layout:
  //   [0, 10.5MB)  Afr  (tap fragments; dead after conv)
  //   [0, 16MB)    Wb   (bf16 W; written AFTER conv reads Afr -- same stream)
  //   [16MB, 48MB) Am   (bf16 activations)
  char* ws = (char*)d_ws;
  unsigned short* Afr = (unsigned short*)ws;
  __hip_bfloat16* Wb  = (__hip_bfloat16*)ws;
  unsigned short* Am  = (unsigned short*)(ws + (16 << 20));

  tapfrag_kernel<<<(Hc * 5 * 64) / 256, 256, 0, stream>>>(kin, Afr);
  conv_mfma_kernel<<<dim3(Lc / 512, Hc / 16, Bc), 256, 0, stream>>>(u, Afr, Dp, Am);
  wcast_kernel<<<(2 * Hc * Hc) / 1024, 256, 0, stream>>>(W, Wb);
  gemm_glu_kernel<<<dim3((Bc * Lc / 256) * (Hc / 128)), 512, 0, stream>>>(
      (const __hip_bfloat16*)Am, Wb, bias, out);
}

// Round 7
// 325.695 us; speedup vs baseline: 1.1588x; 1.0015x over previous
//
#include <hip/hip_runtime.h>
#include <hip/hip_bf16.h>
#include <cstdint>

// Problem dims (fixed by reference setup_inputs)
constexpr int Bc  = 2;
constexpr int Lc  = 4096;
constexpr int Hc  = 2048;
constexpr int LKc = 128;
constexpr float LAMc = 0.003f;

typedef __attribute__((ext_vector_type(8))) __bf16 bf16x8;
typedef __attribute__((ext_vector_type(4))) float  f32x4;
typedef __attribute__((ext_vector_type(8))) unsigned short ushort8;

__device__ __forceinline__ unsigned short f2bf_bits(float v) {
  union { __hip_bfloat16 b; unsigned short u; } cv;
  cv.b = __float2bfloat16(v);
  return cv.u;
}
__device__ __forceinline__ float bf_bits2f(unsigned short u) {
  union { unsigned int i; float f; } cv;
  cv.i = ((unsigned int)u) << 16;
  return cv.f;
}

// ---------------------------------------------------------------------------
// async global->LDS, 16B per lane. LDS dest is the WAVE-UNIFORM base; HW adds
// lane*16. Global src is per-lane (pre-gathered fragment order).
// ---------------------------------------------------------------------------
__device__ __forceinline__ void gl_lds16(const void* g, void* lds) {
  __builtin_amdgcn_global_load_lds(
      (const __attribute__((address_space(1))) uint32_t*)(uintptr_t)g,
      (__attribute__((address_space(3))) uint32_t*)(uint32_t)(uintptr_t)lds,
      16, 0, 0);
}

// ---------------------------------------------------------------------------
// Kernel 1: tap squash + Hankel MFMA A-fragment precompute (unchanged).
// ---------------------------------------------------------------------------
__global__ __launch_bounds__(256) void tapfrag_kernel(
    const float* __restrict__ kin, unsigned short* __restrict__ Afr) {
  const int idx  = blockIdx.x * 256 + threadIdx.x;  // [0, 2048*5*64)
  const int lane = idx & 63;
  const int idx2 = idx >> 6;          // h*5 + cc
  const int h  = idx2 / 5;
  const int cc = idx2 - h * 5;
  const int m = lane & 15, quad = lane >> 4;
  const int jb = m + 32 * cc - 32 + 8 * quad;
  ushort8 o;
#pragma unroll
  for (int jj = 0; jj < 8; ++jj) {
    const int j = jb + jj;
    float v = 0.f;
    if (j >= 0 && j < LKc) {
      const float x = kin[h * LKc + j];
      const float a = fabsf(x) - LAMc;
      v = (a > 0.f) ? copysignf(a, x) : 0.f;
    }
    o[jj] = f2bf_bits(v);
  }
  ((ushort8*)Afr)[idx] = o;
}

// ---------------------------------------------------------------------------
// Kernel 2: W fp32 [2H, H] -> bf16 same layout (unchanged).
// ---------------------------------------------------------------------------
__global__ __launch_bounds__(256) void wcast_kernel(
    const float* __restrict__ W, __hip_bfloat16* __restrict__ Wb) {
  const int idx = (blockIdx.x * 256 + threadIdx.x) * 4;
  const float4 v = *(const float4*)(W + idx);
  Wb[idx + 0] = __float2bfloat16(v.x);
  Wb[idx + 1] = __float2bfloat16(v.y);
  Wb[idx + 2] = __float2bfloat16(v.z);
  Wb[idx + 3] = __float2bfloat16(v.w);
}

// ---------------------------------------------------------------------------
// Kernel 3 (v3): MFMA FIR conv.
//  - float4 staging (r6-verified)
//  - NEW: Afr fragment software-prefetch: hi=0 frags load BEFORE staging
//    (latency under u loads); hi+1 frags load at iteration top (latency under
//    hi's 10 MFMAs); register rotation, unroll-1 kept for VGPR control.
//  - NEW: tanh-form GELU y*sigmoid(y*(c1 + c3*y^2)) via __expf + v_rcp
//    (~8 branchless instr) replacing erff (~50 branchy). Max abs deviation
//    ~3e-4 << bf16 quantization of Am.
// ---------------------------------------------------------------------------
__global__ __launch_bounds__(256) void conv_mfma_kernel(
    const float* __restrict__ u, const unsigned short* __restrict__ Afr,
    const float* __restrict__ Dp, unsigned short* __restrict__ Am) {
  __shared__ __align__(16) unsigned short ur[16 * 664];  // 21248 B
  __shared__ __align__(16) unsigned short ot[512 * 17];  // 17408 B

  const int t    = threadIdx.x;
  const int lane = t & 63;
  const int wv   = t >> 6;
  const int l16  = lane & 15;
  const int quad = lane >> 4;
  const int l0 = blockIdx.x * 512;
  const int h0 = blockIdx.y * 16;
  const int b  = blockIdx.z;

  const size_t ubase = (size_t)b * Lc * Hc + h0;

  // ---- Afr prefetch for hi=0: issued before staging, lands during it
  const unsigned short* afp0 =
      Afr + ((size_t)((h0 + (wv << 2)) * 5) * 64 + lane) * 8;
  bf16x8 afc[5];
#pragma unroll
  for (int cc = 0; cc < 5; ++cc) afc[cc] = *(const bf16x8*)(afp0 + cc * 512);

  // ---- stage 16 h x 656 l (reversed, bf16) via float4: 2624 units, 11 iters
#pragma unroll
  for (int i = 0; i < 11; ++i) {
    const int e = i * 256 + t;
    if (e < 2624) {
      const int x  = e >> 2;          // 0..655
      const int hq = (e & 3) << 2;    // 0,4,8,12
      const int l  = l0 + 528 - x;
      float4 v = make_float4(0.f, 0.f, 0.f, 0.f);
      if (l >= 0)
        v = *(const float4*)(u + ubase + (size_t)min(l, Lc - 1) * Hc + hq);
      ur[(hq + 0) * 664 + x] = f2bf_bits(v.x);
      ur[(hq + 1) * 664 + x] = f2bf_bits(v.y);
      ur[(hq + 2) * 664 + x] = f2bf_bits(v.z);
      ur[(hq + 3) * 664 + x] = f2bf_bits(v.w);
    }
  }
  __syncthreads();

#pragma unroll 1
  for (int hi = 0; hi < 4; ++hi) {
    const int hl = (wv << 2) | hi;
    const int h  = h0 + hl;
    // prefetch next hi's taps; latency overlaps this hi's MFMA cluster
    bf16x8 afn[5];
    if (hi < 3) {
      const unsigned short* afp = afp0 + (size_t)(hi + 1) * 5 * 512;
#pragma unroll
      for (int cc = 0; cc < 5; ++cc) afn[cc] = *(const bf16x8*)(afp + cc * 512);
    }
    const float dv = 2.f * Dp[h];
    const unsigned short* urh = &ur[hl * 664];
#pragma unroll
    for (int nt = 0; nt < 2; ++nt) {
      f32x4 acc = f32x4{0.f, 0.f, 0.f, 0.f};
      const int bbase = 496 - 256 * nt - 16 * l16 + 8 * quad;
#pragma unroll
      for (int cc = 0; cc < 5; ++cc) {
        const bf16x8 bf = *(const bf16x8*)(urh + bbase + 32 * cc);
        acc = __builtin_amdgcn_mfma_f32_16x16x32_bf16(afc[cc], bf, acc, 0, 0, 0);
      }
#pragma unroll
      for (int r = 0; r < 4; ++r) {
        const int lc = quad * 4 + r + 16 * l16;
        const float uu = bf_bits2f(urh[528 - 256 * nt - lc]);
        const float y = fmaf(dv, uu, acc[r]);
        // GELU (tanh form): y * sigmoid(y*(1.5957691 + 0.07135482*y^2))
        const float z = y * fmaf(0.07135481627f, y * y, 1.5957691216f);
        const float g = y * __builtin_amdgcn_rcpf(1.f + __expf(-z));
        ot[(nt * 256 + lc) * 17 + hl] = f2bf_bits(g);
      }
    }
    if (hi < 3) {
#pragma unroll
      for (int cc = 0; cc < 5; ++cc) afc[cc] = afn[cc];
    }
  }
  __syncthreads();

#pragma unroll
  for (int rr = 0; rr < 2; ++rr) {
    const int lc = (rr << 8) + t;
    const unsigned short* row = &ot[lc * 17];
    unsigned int w[8];
#pragma unroll
    for (int p = 0; p < 8; ++p)
      w[p] = (unsigned int)row[2 * p] | ((unsigned int)row[2 * p + 1] << 16);
    unsigned short* dst = Am + ((size_t)(b * Lc + l0 + lc)) * Hc + h0;
    *(uint4*)(dst)     = make_uint4(w[0], w[1], w[2], w[3]);
    *(uint4*)(dst + 8) = make_uint4(w[4], w[5], w[6], w[7]);
  }
}

// ---------------------------------------------------------------------------
// Kernel 4 (v5, FROZEN): latency-tolerant GEMM + bias + GLU.
//  - 4-slot LDS ring, staged 3 K-tiles ahead, vmcnt(8) boundary wait
//  - L2-locality XCD remap (FETCH 270->148 MB verified r5)
//  - fragment-packed LDS -> 0 bank conflicts (r1-verified)
// ---------------------------------------------------------------------------
constexpr int KTILES = Hc / 32;  // 64

__global__ __launch_bounds__(512, 2) void gemm_glu_kernel(
    const __hip_bfloat16* __restrict__ A, const __hip_bfloat16* __restrict__ Wb,
    const float* __restrict__ bias, float* __restrict__ out) {
  __shared__ __align__(16) char lds[131072];  // 4 slots x (A 16KB + B 16KB)

  const int t    = threadIdx.x;
  const int lane = t & 63;
  const int w    = t >> 6;        // wave 0..7
  const int l16  = lane & 15;
  const int quad = lane >> 4;
  const int wr   = w >> 2;        // 0..1 : M band
  const int wc   = w & 3;         // 0..3 : N band

  // bijective XCD-locality remap: xcd = bid&7 (HW round-robin), s = bid>>3.
  const int bid = blockIdx.x;     // 0..511
  const int xcd = bid & 7;
  const int s   = bid >> 3;       // 0..63
  const int m0g = (xcd * 4 + (s >> 4)) * 256;
  const int n0  = (s & 15) * 128;

  // per-thread pre-gathered staging sources: idx 0,1 = A units, 2,3 = B units
  const __hip_bfloat16* gsrc[4];
#pragma unroll
  for (int u = 0; u < 2; ++u) {
    const int f = u * 8 + w;  // fragment index 0..15 staged by this wave
    gsrc[u] = A + (size_t)(m0g + f * 16 + l16) * Hc + quad * 8;
    const int wrow = ((f >> 1) & 1) * Hc + n0 + (f >> 2) * 32 + (f & 1) * 16 + l16;
    gsrc[2 + u] = Wb + (size_t)wrow * Hc + quad * 8;
  }

  f32x4 acc[8][4];
#pragma unroll
  for (int i = 0; i < 8; ++i)
#pragma unroll
    for (int j = 0; j < 4; ++j) acc[i][j] = f32x4{0.f, 0.f, 0.f, 0.f};

// wave-uniform LDS dest: slot + region + frag run; HW adds lane*16
#define STAGE(tile, idx)                                                      \
  gl_lds16(gsrc[idx] + (size_t)(tile) * 32,                                   \
           lds + ((tile) & 3) * 32768 + (((idx) >> 1) & 1) * 16384 +          \
               (((idx) & 1) * 8 + w) * 1024)

  // prologue: K-tiles 0,1,2 (4 loads/lane each, 12 outstanding)
#pragma unroll
  for (int i = 0; i < 4; ++i) STAGE(0, i);
#pragma unroll
  for (int i = 0; i < 4; ++i) STAGE(1, i);
#pragma unroll
  for (int i = 0; i < 4; ++i) STAGE(2, i);
  asm volatile("s_waitcnt vmcnt(8)" ::: "memory");  // tile 0 landed
  __builtin_amdgcn_s_barrier();

  const char* sAbase = lds + wr * 8192 + lane * 16;
  const char* sBbase = lds + 16384 + wc * 4096 + lane * 16;

  // One BK=32 K-tile: {12 ds_read || 4 stage(kt+3) || 32 MFMA} -> vmcnt(N)
  // -> barrier.  Steady-state VMN=8 (tiles kt+2,kt+3 in flight; kt+1 landed).
#define KTILE_BODY(KT, DO_STAGE, VMN)                                         \
  {                                                                           \
    const char* sA = sAbase + ((KT) & 3) * 32768;                             \
    const char* sB = sBbase + ((KT) & 3) * 32768;                             \
    bf16x8 afr[8], bfr[4];                                                    \
    _Pragma("unroll") for (int i = 0; i < 4; ++i)                             \
        bfr[i] = *(const bf16x8*)(sB + i * 1024);                             \
    _Pragma("unroll") for (int i = 0; i < 8; ++i)                             \
        afr[i] = *(const bf16x8*)(sA + i * 1024);                             \
    if (DO_STAGE) {                                                           \
      STAGE((KT) + 3, 0); STAGE((KT) + 3, 1);                                 \
      STAGE((KT) + 3, 2); STAGE((KT) + 3, 3);                                 \
    }                                                                         \
    __builtin_amdgcn_s_setprio(1);                                            \
    _Pragma("unroll") for (int mf = 0; mf < 8; ++mf)                          \
        _Pragma("unroll") for (int nf = 0; nf < 4; ++nf)                      \
            acc[mf][nf] = __builtin_amdgcn_mfma_f32_16x16x32_bf16(            \
                afr[mf], bfr[nf], acc[mf][nf], 0, 0, 0);                      \
    __builtin_amdgcn_s_setprio(0);                                            \
    asm volatile("s_waitcnt vmcnt(" #VMN ")" ::: "memory");                   \
    __builtin_amdgcn_s_barrier();                                             \
  }

  // main loop: tiles 0..59 (unroll 4 folds slot offsets), staging kt+3
#pragma unroll 1
  for (int k4 = 0; k4 < 15; ++k4) {
    const int kt = k4 * 4;
    KTILE_BODY(kt + 0, true, 8)
    KTILE_BODY(kt + 1, true, 8)
    KTILE_BODY(kt + 2, true, 8)
    KTILE_BODY(kt + 3, true, 8)
  }
  // tail: tile 60 stages 63 (last); then drain 8 -> 4 -> 0
  KTILE_BODY(60, true, 8)
  KTILE_BODY(61, false, 4)
  KTILE_BODY(62, false, 0)
  KTILE_BODY(63, false, 0)
#undef KTILE_BODY
#undef STAGE

  // ---------- epilogue: lane-local GLU (a at nf, g at nf+2), coalesced rows
  const int mwb = m0g + wr * 128 + quad * 4;
  const int nb  = n0 + wc * 32 + l16;
#pragma unroll
  for (int j = 0; j < 2; ++j) {
    const int n = nb + j * 16;
    const float ba = bias[n];
    const float bg = bias[Hc + n];
#pragma unroll
    for (int mf = 0; mf < 8; ++mf) {
#pragma unroll
      for (int r = 0; r < 4; ++r) {
        const float a = acc[mf][j][r] + ba;
        const float g = acc[mf][j + 2][r] + bg;
        out[(size_t)(mwb + mf * 16 + r) * Hc + n] = a * (1.f / (1.f + expf(-g)));
      }
    }
  }
}

// ---------------------------------------------------------------------------
extern "C" void kernel_launch(void* const* d_in, const int* in_sizes, int n_in,
                              void* d_out, int out_size, void* d_ws, size_t ws_size,
                              hipStream_t stream) {
  const float* u    = (const float*)d_in[0];  // [B, L, H]
  const float* kin  = (const float*)d_in[1];  // [1, H, LK]
  const float* Dp   = (const float*)d_in[2];  // [1, H]
  const float* W    = (const float*)d_in[3];  // [2H, H]
  const float* bias = (const float*)d_in[4];  // [2H]
  float* out = (float*)d_out;                 // [B, L, H]

  // ws layout:
  //   [0, 10.5MB)  Afr  (tap fragments; dead after conv)
  //   [0, 16MB)    Wb   (bf16 W; written AFTER conv reads Afr -- same stream)
  //   [16MB, 48MB) Am   (bf16 activations)
  char* ws = (char*)d_ws;
  unsigned short* Afr = (unsigned short*)ws;
  __hip_bfloat16* Wb  = (__hip_bfloat16*)ws;
  unsigned short* Am  = (unsigned short*)(ws + (16 << 20));

  tapfrag_kernel<<<(Hc * 5 * 64) / 256, 256, 0, stream>>>(kin, Afr);
  conv_mfma_kernel<<<dim3(Lc / 512, Hc / 16, Bc), 256, 0, stream>>>(u, Afr, Dp, Am);
  wcast_kernel<<<(2 * Hc * Hc) / 1024, 256, 0, stream>>>(W, Wb);
  gemm_glu_kernel<<<dim3((Bc * Lc / 256) * (Hc / 128)), 512, 0, stream>>>(
      (const __hip_bfloat16*)Am, Wb, bias, out);
}